// Round 10
// baseline (106.583 us; speedup 1.0000x reference)
//
#include <hip/hip_runtime.h>
#include <hip/hip_bf16.h>
#include <math.h>

// Problem constants
constexpr int B  = 2;
constexpr int C  = 64;
constexpr int H  = 128;
constexpr int W  = 128;
constexpr int O  = 64;
constexpr int DG = 8;
constexpr int K  = 3;
constexpr int KK = K * K;           // 9
constexpr int HW = H * W;           // 16384
constexpr int CG = C / DG;          // 8
constexpr int OM_C  = 3 * DG * KK;  // 216
constexpr int OFF_C = 2 * DG * KK;  // 144
constexpr int MSK_C = DG * KK;      // 72
constexpr float MRM = 10.0f;

typedef unsigned short u16;
typedef short bfx8 __attribute__((ext_vector_type(8)));   // 8 bf16 (4 VGPRs)
typedef float fx4 __attribute__((ext_vector_type(4)));    // MFMA accumulator

// Sizes
constexpr int WT_N   = 576 * 64;        // deform weights, transposed
constexpr int X0T_N  = B * C * HW;      // 2097152 floats (x0 interleaved)
constexpr int STEP_E = 14336;           // u16 per tc-step slab (28 KB)
constexpr int WB_N   = 18 * STEP_E;     // 258048
constexpr int PW     = 130;             // padded width/height
constexpr int PADP   = PW * PW;         // 16900 padded pixels
constexpr int X1P_N  = B * PADP * C;    // 2163200 u16 per buffer

// tap deltas in padded-pixel u16 units: (dy*130+dx)*64
__device__ constexpr int TAPD[9] = {
    (-PW - 1) * 64, (-PW) * 64, (-PW + 1) * 64,
    (-1) * 64,      0,          (1) * 64,
    (PW - 1) * 64,  (PW) * 64,  (PW + 1) * 64
};

// XCD chunk swizzle (512 blocks): XCD x gets 64 consecutive works.
__device__ __forceinline__ int xcd_work(int bid) {
    return ((bid & 7) << 6) + (bid >> 3);
}

// ---------------- prep1: wT, padded x1 bf16 hi/lo, wB ----------------
// x1p layout: [b][ppad 130x130][ic 64] bf16, zero border.
// wB layout (u16): [step 18][nfh 14][wsel 2][lane 64][j 8], step = t*2+chunk
__global__ void __launch_bounds__(256)
prep1_kernel(const float* __restrict__ weight,
             const float* __restrict__ w_om,
             const float* __restrict__ x1,
             float* __restrict__ wT,
             u16* __restrict__ x1p_hi,
             u16* __restrict__ x1p_lo,
             u16* __restrict__ wB) {
    int idx = blockIdx.x * 256 + threadIdx.x;
    if (idx < WT_N) {
        int r = idx / O;          // (g*KK+i)*CG + c
        int o = idx - r * O;
        int g = r / (KK * CG);
        int rem = r - g * (KK * CG);
        int i = rem / CG;
        int c = rem - i * CG;
        wT[idx] = weight[o * (C * KK) + (g * CG + c) * KK + i];
        return;
    }
    int i1 = idx - WT_N;
    if (i1 < B * HW) {   // transpose interior: x1 -> padded [p][ic] hi/lo
        int p = i1 & (HW - 1);
        int b = i1 >> 14;
        const float* xp = x1 + (size_t)b * C * HW + p;
        bfx8 vh[8], vl[8];
#pragma unroll
        for (int k = 0; k < 8; ++k) {
#pragma unroll
            for (int j = 0; j < 8; ++j) {
                float x = xp[(size_t)(k * 8 + j) * HW];
                __hip_bfloat16 hb = __float2bfloat16(x);
                float hf = __bfloat162float(hb);
                __hip_bfloat16 lb = __float2bfloat16(x - hf);
                vh[k][j] = *(short*)&hb;
                vl[k][j] = *(short*)&lb;
            }
        }
        int dpx = ((p >> 7) + 1) * PW + (p & (W - 1)) + 1;
        u16* dh = x1p_hi + ((size_t)b * PADP + dpx) * C;
        u16* dl = x1p_lo + ((size_t)b * PADP + dpx) * C;
#pragma unroll
        for (int k = 0; k < 8; ++k) {
            *(bfx8*)(dh + k * 8) = vh[k];
            *(bfx8*)(dl + k * 8) = vl[k];
        }
        return;
    }
    int i2 = i1 - B * HW;
    if (i2 < B * PADP) {  // zero the border pixels
        int b2 = i2 / PADP;
        int px = i2 - b2 * PADP;
        int rr = px / PW, cc = px - rr * PW;
        if (rr == 0 || rr == PW - 1 || cc == 0 || cc == PW - 1) {
            u16* zh = x1p_hi + ((size_t)b2 * PADP + px) * C;
            u16* zl = x1p_lo + ((size_t)b2 * PADP + px) * C;
            const bfx8 z = {0, 0, 0, 0, 0, 0, 0, 0};
#pragma unroll
            for (int k = 0; k < 8; ++k) {
                *(bfx8*)(zh + k * 8) = z;
                *(bfx8*)(zl + k * 8) = z;
            }
        }
        return;
    }
    int i3 = i2 - B * PADP;
    if (i3 < WB_N) {
        int step = i3 / STEP_E;
        int r    = i3 - step * STEP_E;
        int nfh  = r >> 10;          // 0..13
        int wsel = (r >> 9) & 1;     // 0=hi, 1=lo
        int lane = (r >> 3) & 63;
        int j    = r & 7;
        int t = step >> 1, chunk = step & 1;
        int ic = chunk * 32 + ((lane >> 4) << 3) + j;
        int oc = (nfh << 4) + (lane & 15);
        float v = (oc < OM_C) ? w_om[oc * (C * KK) + ic * KK + t] : 0.0f;
        __hip_bfloat16 hb = __float2bfloat16(v);
        if (wsel == 0) {
            wB[i3] = *(u16*)&hb;
        } else {
            float hf = __bfloat162float(hb);
            __hip_bfloat16 lb = __float2bfloat16(v - hf);
            wB[i3] = *(u16*)&lb;
        }
    }
}

// ---------------- prep2: x0 channel-interleave ----------------
__global__ void __launch_bounds__(256)
prep2_kernel(const float* __restrict__ x0, float* __restrict__ x0T) {
    int idx = blockIdx.x * 256 + threadIdx.x;
    int p  = idx & (HW - 1);
    int ch = (idx >> 14) & (C - 1);
    int b  = idx >> 20;
    x0T[((size_t)((b * DG + (ch >> 3)) * HW + p) << 3) + (ch & 7)] = x0[idx];
}

// ---------------- conv_offset_mask: 9-phase LDS-B pipeline ----------------
// Block = 1024 thr = 16 waves = 4 wrow x 2 wcol x 2 kidc (ic-chunk). Wave
// tile M=32 px x N=112 oc x one 32-ic chunk; 9 tap-phases, one barrier each.
// Both chunks' B slabs double-buffered in LDS (112 KB), staged by 14 waves
// (4 global_load_lds each). A-loads are flat (zero-padded x1p), prefetched
// one phase ahead. Epilogue: chunk-reduction via LDS, fragment-layout store.
__global__ void __launch_bounds__(1024, 4)
conv_om_mfma_kernel(const u16* __restrict__ x1p_hi,
                    const u16* __restrict__ x1p_lo,
                    const u16* __restrict__ wB,
                    const float* __restrict__ b_om,
                    const float* __restrict__ pre_offset,
                    const float* __restrict__ pre_sim,
                    float* __restrict__ offset,
                    float* __restrict__ mask) {
    __shared__ __align__(16) u16 smem[2][2 * STEP_E];   // 112 KB

    int bid  = blockIdx.x;                        // 256 blocks
    int work = ((bid & 7) << 5) + (bid >> 3);     // XCD-chunked
    int b    = work >> 7;
    int px0  = (work & 127) << 7;                 // 128-px tile

    int tid  = threadIdx.x;
    int lane = tid & 63;
    int wid  = tid >> 6;             // 0..15
    int kidc = wid & 1;              // ic-chunk
    int wcol = (wid >> 1) & 1;
    int wrow = wid >> 2;             // 0..3

    fx4 acc[2][7];
#pragma unroll
    for (int mf = 0; mf < 2; ++mf)
#pragma unroll
        for (int nf = 0; nf < 7; ++nf) acc[mf][nf] = fx4{0.f, 0.f, 0.f, 0.f};

    // A base addresses (padded layout, no boundary handling needed)
    int pA   = px0 + wrow * 32 + (lane & 15);
    int klane = (lane >> 4) << 3;
    int base0 = (((pA >> 7) + 1) * PW + (pA & (W - 1)) + 1) * C + kidc * 32 + klane;
    int base1 = base0 + 16 * C;      // mf=1 (+16 px, same row)

    const u16* xh_b = x1p_hi + (size_t)b * PADP * C;
    const u16* xl_b = x1p_lo + (size_t)b * PADP * C;

    // staging role: 14 waves x 4 insts cover 56 x 1KB slots (both chunks)
    bool stager = (wid < 14);
    int  soff[4];
#pragma unroll
    for (int k = 0; k < 4; ++k) {
        int s  = wid * 4 + k;        // 0..55
        int cs = s / 28;             // chunk
        int wi = s - cs * 28;
        soff[k] = cs * STEP_E + wi * 512 + lane * 8;
    }

    // prologue: stage tap 0 (both chunks), load A(tap 0)
    if (stager) {
#pragma unroll
        for (int k = 0; k < 4; ++k) {
            __builtin_amdgcn_global_load_lds(
                (const __attribute__((address_space(1))) u16*)(wB + soff[k]),
                (__attribute__((address_space(3))) u16*)(&smem[0][0] + soff[k]),
                16, 0, 0);
        }
    }
    bfx8 ahc0 = *(const bfx8*)(xh_b + base0 + TAPD[0]);
    bfx8 ahc1 = *(const bfx8*)(xh_b + base1 + TAPD[0]);
    bfx8 alc0 = *(const bfx8*)(xl_b + base0 + TAPD[0]);
    bfx8 alc1 = *(const bfx8*)(xl_b + base1 + TAPD[0]);
    __syncthreads();

#pragma unroll
    for (int t = 0; t < 9; ++t) {
        bfx8 ahn0, ahn1, aln0, aln1;
        if (t < 8) {
            if (stager) {
                const u16* src = wB + (size_t)(t + 1) * 2 * STEP_E;
                u16* dst = &smem[(t + 1) & 1][0];
#pragma unroll
                for (int k = 0; k < 4; ++k) {
                    __builtin_amdgcn_global_load_lds(
                        (const __attribute__((address_space(1))) u16*)(src + soff[k]),
                        (__attribute__((address_space(3))) u16*)(dst + soff[k]),
                        16, 0, 0);
                }
            }
            int d = TAPD[t + 1];
            ahn0 = *(const bfx8*)(xh_b + base0 + d);
            ahn1 = *(const bfx8*)(xh_b + base1 + d);
            aln0 = *(const bfx8*)(xl_b + base0 + d);
            aln1 = *(const bfx8*)(xl_b + base1 + d);
        }
        const u16* slab = &smem[t & 1][kidc * STEP_E];
#pragma unroll
        for (int nf = 0; nf < 7; ++nf) {
            const u16* bp = slab + (((wcol * 7 + nf) << 10) + (lane << 3));
            bfx8 bh = *(const bfx8*)bp;
            bfx8 bl = *(const bfx8*)(bp + 512);
            acc[0][nf] = __builtin_amdgcn_mfma_f32_16x16x32_bf16(ahc0, bh, acc[0][nf], 0, 0, 0);
            acc[0][nf] = __builtin_amdgcn_mfma_f32_16x16x32_bf16(alc0, bh, acc[0][nf], 0, 0, 0);
            acc[0][nf] = __builtin_amdgcn_mfma_f32_16x16x32_bf16(ahc0, bl, acc[0][nf], 0, 0, 0);
            acc[1][nf] = __builtin_amdgcn_mfma_f32_16x16x32_bf16(ahc1, bh, acc[1][nf], 0, 0, 0);
            acc[1][nf] = __builtin_amdgcn_mfma_f32_16x16x32_bf16(alc1, bh, acc[1][nf], 0, 0, 0);
            acc[1][nf] = __builtin_amdgcn_mfma_f32_16x16x32_bf16(ahc1, bl, acc[1][nf], 0, 0, 0);
        }
        __syncthreads();
        if (t < 8) {
            ahc0 = ahn0; ahc1 = ahn1; alc0 = aln0; alc1 = aln1;
        }
    }

    // chunk reduction through LDS (reuse smem as 8-slot fx4 buffer, 112 KB).
    fx4* red = (fx4*)&smem[0][0];
    int slot = wrow * 2 + wcol;      // 0..7
    if (kidc) {
#pragma unroll
        for (int mf = 0; mf < 2; ++mf)
#pragma unroll
            for (int nf = 0; nf < 7; ++nf)
                red[(slot * 14 + mf * 7 + nf) * 64 + lane] = acc[mf][nf];
    }
    __syncthreads();
    if (!kidc) {
        // Epilogue from fragment layout: col(oc)=lane&15, row(pix)=(lane>>4)*4+r.
#pragma unroll
        for (int mf = 0; mf < 2; ++mf) {
#pragma unroll
            for (int nf = 0; nf < 7; ++nf) {
                fx4 v = acc[mf][nf] + red[(slot * 14 + mf * 7 + nf) * 64 + lane];
                int oc  = wcol * 112 + nf * 16 + (lane & 15);
                int pix = px0 + wrow * 32 + mf * 16 + ((lane >> 4) << 2);
                if (oc < OM_C) {
                    float bb = b_om[oc];
                    if (oc < OFF_C) {
                        size_t oi = (size_t)(b * OFF_C + oc) * HW + pix;
                        float4 po = *(const float4*)&pre_offset[oi];
                        float4 r;
                        r.x = MRM * tanhf(v[0] + bb) + po.x;
                        r.y = MRM * tanhf(v[1] + bb) + po.y;
                        r.z = MRM * tanhf(v[2] + bb) + po.z;
                        r.w = MRM * tanhf(v[3] + bb) + po.w;
                        *(float4*)&offset[oi] = r;
                    } else {
                        size_t mi = (size_t)(b * MSK_C + oc - OFF_C) * HW + pix;
                        float4 ps = *(const float4*)&pre_sim[mi];
                        float4 r;
                        r.x = 1.0f / (1.0f + expf(-(v[0] + bb) * ps.x));
                        r.y = 1.0f / (1.0f + expf(-(v[1] + bb) * ps.y));
                        r.z = 1.0f / (1.0f + expf(-(v[2] + bb) * ps.z));
                        r.w = 1.0f / (1.0f + expf(-(v[3] + bb) * ps.w));
                        *(float4*)&mask[mi] = r;
                    }
                }
            }
        }
    }
}

// ---------------- Kernel: modulated deformable conv -----------------------
__global__ void __launch_bounds__(512, 4)
deform_conv_kernel(const float* __restrict__ x0T,
                   const float* __restrict__ offset,
                   const float* __restrict__ mask,
                   const float* __restrict__ wT,
                   const float* __restrict__ bias,
                   float* __restrict__ out) {
    __shared__ float red[8 * 64 * 9];   // 18 KB

    int work  = xcd_work(blockIdx.x);
    int pbase = (work & 255) * 64;
    int b     = work >> 8;

    int tid  = threadIdx.x;
    int lane = tid & 63;
    int g    = __builtin_amdgcn_readfirstlane(tid >> 6);  // wave-uniform
    int p = pbase + lane;
    int h = p >> 7;
    int w = p & (W - 1);

    float acc[O];
#pragma unroll
    for (int o = 0; o < O; ++o) acc[o] = 0.0f;

    const float* offb = offset + (size_t)b * OFF_C * HW + p;
    const float* mb   = mask + (size_t)b * MSK_C * HW + p;
    const float* xg   = x0T + ((size_t)(b * DG + g) * HW) * CG;

    for (int i = 0; i < KK; ++i) {
        int gi = g * KK + i;
        float offy = offb[(2 * gi) * HW];
        float offx = offb[(2 * gi + 1) * HW];
        float m    = mb[gi * HW];

        float py = offy + (float)(h - 1 + i / 3);
        float px = offx + (float)(w - 1 + i % 3);
        float fy = floorf(py), fx = floorf(px);
        float ly = py - fy, lx = px - fx;
        float hy = 1.0f - ly, hx = 1.0f - lx;
        int y0 = (int)fy, x0i = (int)fx;
        int y1 = y0 + 1, x1i = x0i + 1;
        bool vy0 = (y0 >= 0) && (y0 < H);
        bool vy1 = (y1 >= 0) && (y1 < H);
        bool vx0 = (x0i >= 0) && (x0i < W);
        bool vx1 = (x1i >= 0) && (x1i < W);
        int cy0 = min(max(y0, 0), H - 1), cy1 = min(max(y1, 0), H - 1);
        int cx0 = min(max(x0i, 0), W - 1), cx1 = min(max(x1i, 0), W - 1);
        float w00 = hy * hx * ((vy0 && vx0) ? 1.0f : 0.0f) * m;
        float w01 = hy * lx * ((vy0 && vx1) ? 1.0f : 0.0f) * m;
        float w10 = ly * hx * ((vy1 && vx0) ? 1.0f : 0.0f) * m;
        float w11 = ly * lx * ((vy1 && vx1) ? 1.0f : 0.0f) * m;
        int i00 = cy0 * W + cx0, i01 = cy0 * W + cx1;
        int i10 = cy1 * W + cx0, i11 = cy1 * W + cx1;

        const float4* A  = (const float4*)(xg + (size_t)i00 * CG);
        const float4* Bc = (const float4*)(xg + (size_t)i01 * CG);
        const float4* Cc = (const float4*)(xg + (size_t)i10 * CG);
        const float4* Dc = (const float4*)(xg + (size_t)i11 * CG);
        float4 a0 = A[0],  a1 = A[1];
        float4 b0 = Bc[0], b1 = Bc[1];
        float4 c0 = Cc[0], c1 = Cc[1];
        float4 d0 = Dc[0], d1 = Dc[1];

        float v[CG];
        v[0] = w00 * a0.x + w01 * b0.x + w10 * c0.x + w11 * d0.x;
        v[1] = w00 * a0.y + w01 * b0.y + w10 * c0.y + w11 * d0.y;
        v[2] = w00 * a0.z + w01 * b0.z + w10 * c0.z + w11 * d0.z;
        v[3] = w00 * a0.w + w01 * b0.w + w10 * c0.w + w11 * d0.w;
        v[4] = w00 * a1.x + w01 * b1.x + w10 * c1.x + w11 * d1.x;
        v[5] = w00 * a1.y + w01 * b1.y + w10 * c1.y + w11 * d1.y;
        v[6] = w00 * a1.z + w01 * b1.z + w10 * c1.z + w11 * d1.z;
        v[7] = w00 * a1.w + w01 * b1.w + w10 * c1.w + w11 * d1.w;

        const float* wrow = wT + (size_t)(gi * CG) * O;   // wave-uniform
#pragma unroll
        for (int c = 0; c < CG; ++c) {
#pragma unroll
            for (int o = 0; o < O; ++o)
                acc[o] = fmaf(v[c], wrow[c * O + o], acc[o]);
        }
    }

    // Cross-group reduction: 8 chunks of 8 output channels.
    int ocp = tid >> 6;
#pragma unroll
    for (int chunk = 0; chunk < 8; ++chunk) {
        float* slot = &red[(g * 64 + lane) * 9];
#pragma unroll
        for (int j = 0; j < 8; ++j) slot[j] = acc[chunk * 8 + j];
        __syncthreads();
        float s = 0.0f;
#pragma unroll
        for (int wv = 0; wv < 8; ++wv) s += red[(wv * 64 + lane) * 9 + ocp];
        int oc = chunk * 8 + ocp;
        out[((size_t)b * O + oc) * HW + pbase + lane] = s + bias[oc];
        __syncthreads();
    }
}

// ---------------- Launch ----------------
extern "C" void kernel_launch(void* const* d_in, const int* in_sizes, int n_in,
                              void* d_out, int out_size, void* d_ws, size_t ws_size,
                              hipStream_t stream) {
    (void)in_sizes; (void)n_in; (void)out_size; (void)ws_size;
    const float* x0         = (const float*)d_in[0];
    const float* x1         = (const float*)d_in[1];
    const float* pre_offset = (const float*)d_in[2];
    const float* pre_sim    = (const float*)d_in[3];
    const float* weight     = (const float*)d_in[4];
    const float* bias       = (const float*)d_in[5];
    const float* w_om       = (const float*)d_in[6];
    const float* b_om       = (const float*)d_in[7];
    float* out = (float*)d_out;

    // ws layout (floats):
    float* offset = (float*)d_ws;                       // B*144*HW
    float* mask   = offset + (size_t)B * OFF_C * HW;    // B*72*HW
    float* wT     = mask + (size_t)B * MSK_C * HW;      // 36864
    float* xbuf   = wT + WT_N;                          // union region
    u16*   x1p_hi = (u16*)xbuf;                         // X1P_N u16 (padded)
    u16*   x1p_lo = x1p_hi + (size_t)X1P_N;             // X1P_N u16
    u16*   wB     = x1p_lo + (size_t)X1P_N;             // WB_N u16
    float* x0T    = xbuf;                               // reuses x1p (after conv)

    {
        int total = WT_N + B * HW + B * PADP + WB_N;   // 361480
        prep1_kernel<<<(total + 255) / 256, 256, 0, stream>>>(
            weight, w_om, x1, wT, x1p_hi, x1p_lo, wB);
    }
    {
        conv_om_mfma_kernel<<<256, 1024, 0, stream>>>(
            x1p_hi, x1p_lo, wB, b_om, pre_offset, pre_sim, offset, mask);
    }
    {
        prep2_kernel<<<X0T_N / 256, 256, 0, stream>>>(x0, x0T);
    }
    {
        deform_conv_kernel<<<512, 512, 0, stream>>>(
            x0T, offset, mask, wT, bias, out);
    }
}

// Round 11
// 105.279 us; speedup vs baseline: 1.0124x; 1.0124x over previous
//
#include <hip/hip_runtime.h>
#include <hip/hip_bf16.h>
#include <math.h>

// Problem constants
constexpr int B  = 2;
constexpr int C  = 64;
constexpr int H  = 128;
constexpr int W  = 128;
constexpr int O  = 64;
constexpr int DG = 8;
constexpr int K  = 3;
constexpr int KK = K * K;           // 9
constexpr int HW = H * W;           // 16384
constexpr int CG = C / DG;          // 8
constexpr int OM_C  = 3 * DG * KK;  // 216
constexpr int OFF_C = 2 * DG * KK;  // 144
constexpr int MSK_C = DG * KK;      // 72
constexpr float MRM = 10.0f;

typedef unsigned short u16;
typedef short bfx8 __attribute__((ext_vector_type(8)));   // 8 bf16 (4 VGPRs)
typedef float fx4 __attribute__((ext_vector_type(4)));    // MFMA accumulator

// Sizes
constexpr int WT_N   = 576 * 64;        // deform weights, transposed
constexpr int X0T_N  = B * C * HW;      // 2097152 floats (x0 interleaved)
constexpr int STEP_E = 14336;           // u16 per tc-step slab (28 KB)
constexpr int WB_N   = 18 * STEP_E;     // 258048
constexpr int PW     = 130;             // padded width/height
constexpr int PADP   = PW * PW;         // 16900 padded pixels
constexpr int X1P_N  = B * PADP * C;    // u16 per buffer
constexpr int OMS    = 217;             // om LDS stride (floats per pixel)

// tap deltas in padded-pixel u16 units: (dy*130+dx)*64
__device__ constexpr int TAPD[9] = {
    (-PW - 1) * 64, (-PW) * 64, (-PW + 1) * 64,
    (-1) * 64,      0,          (1) * 64,
    (PW - 1) * 64,  (PW) * 64,  (PW + 1) * 64
};

// ---------------- prep1: wT, padded x1 bf16 hi/lo, wB ----------------
__global__ void __launch_bounds__(256)
prep1_kernel(const float* __restrict__ weight,
             const float* __restrict__ w_om,
             const float* __restrict__ x1,
             float* __restrict__ wT,
             u16* __restrict__ x1p_hi,
             u16* __restrict__ x1p_lo,
             u16* __restrict__ wB) {
    int idx = blockIdx.x * 256 + threadIdx.x;
    if (idx < WT_N) {
        int r = idx / O;          // (g*KK+i)*CG + c
        int o = idx - r * O;
        int g = r / (KK * CG);
        int rem = r - g * (KK * CG);
        int i = rem / CG;
        int c = rem - i * CG;
        wT[idx] = weight[o * (C * KK) + (g * CG + c) * KK + i];
        return;
    }
    int i1 = idx - WT_N;
    if (i1 < B * HW) {   // transpose interior: x1 -> padded [p][ic] hi/lo
        int p = i1 & (HW - 1);
        int b = i1 >> 14;
        const float* xp = x1 + (size_t)b * C * HW + p;
        bfx8 vh[8], vl[8];
#pragma unroll
        for (int k = 0; k < 8; ++k) {
#pragma unroll
            for (int j = 0; j < 8; ++j) {
                float x = xp[(size_t)(k * 8 + j) * HW];
                __hip_bfloat16 hb = __float2bfloat16(x);
                float hf = __bfloat162float(hb);
                __hip_bfloat16 lb = __float2bfloat16(x - hf);
                vh[k][j] = *(short*)&hb;
                vl[k][j] = *(short*)&lb;
            }
        }
        int dpx = ((p >> 7) + 1) * PW + (p & (W - 1)) + 1;
        u16* dh = x1p_hi + ((size_t)b * PADP + dpx) * C;
        u16* dl = x1p_lo + ((size_t)b * PADP + dpx) * C;
#pragma unroll
        for (int k = 0; k < 8; ++k) {
            *(bfx8*)(dh + k * 8) = vh[k];
            *(bfx8*)(dl + k * 8) = vl[k];
        }
        return;
    }
    int i2 = i1 - B * HW;
    if (i2 < B * PADP) {  // zero the border pixels
        int b2 = i2 / PADP;
        int px = i2 - b2 * PADP;
        int rr = px / PW, cc = px - rr * PW;
        if (rr == 0 || rr == PW - 1 || cc == 0 || cc == PW - 1) {
            u16* zh = x1p_hi + ((size_t)b2 * PADP + px) * C;
            u16* zl = x1p_lo + ((size_t)b2 * PADP + px) * C;
            const bfx8 z = {0, 0, 0, 0, 0, 0, 0, 0};
#pragma unroll
            for (int k = 0; k < 8; ++k) {
                *(bfx8*)(zh + k * 8) = z;
                *(bfx8*)(zl + k * 8) = z;
            }
        }
        return;
    }
    int i3 = i2 - B * PADP;
    if (i3 < WB_N) {
        int step = i3 / STEP_E;
        int r    = i3 - step * STEP_E;
        int nfh  = r >> 10;          // 0..13
        int wsel = (r >> 9) & 1;     // 0=hi, 1=lo
        int lane = (r >> 3) & 63;
        int j    = r & 7;
        int t = step >> 1, chunk = step & 1;
        int ic = chunk * 32 + ((lane >> 4) << 3) + j;
        int oc = (nfh << 4) + (lane & 15);
        float v = (oc < OM_C) ? w_om[oc * (C * KK) + ic * KK + t] : 0.0f;
        __hip_bfloat16 hb = __float2bfloat16(v);
        if (wsel == 0) {
            wB[i3] = *(u16*)&hb;
        } else {
            float hf = __bfloat162float(hb);
            __hip_bfloat16 lb = __float2bfloat16(v - hf);
            wB[i3] = *(u16*)&lb;
        }
    }
}

// ---------------- prep2: x0 channel-interleave ----------------
__global__ void __launch_bounds__(256)
prep2_kernel(const float* __restrict__ x0, float* __restrict__ x0T) {
    int idx = blockIdx.x * 256 + threadIdx.x;
    int p  = idx & (HW - 1);
    int ch = (idx >> 14) & (C - 1);
    int b  = idx >> 20;
    x0T[((size_t)((b * DG + (ch >> 3)) * HW + p) << 3) + (ch & 7)] = x0[idx];
}

// ---------------- FUSED: conv_offset_mask + transform + deform conv -------
// Block = 1024 thr = 16 waves, one image row (128 px). Phase 1: R10's 9-phase
// LDS-B MFMA conv (acc in regs). Phase 2: kid handoff in 4 rounds via red2,
// kid0 applies tanh/sigmoid and writes offset/mask to LDS om[px][217].
// Phase 3: all 16 waves run deform (wave = pxhalf x group), offsets from LDS,
// x0T gathers from global, oc-reduction via red2. offset/mask never touch HBM.
__global__ void __launch_bounds__(1024, 4)
fused_kernel(const u16* __restrict__ x1p_hi,
             const u16* __restrict__ x1p_lo,
             const u16* __restrict__ wB,
             const float* __restrict__ b_om,
             const float* __restrict__ pre_offset,
             const float* __restrict__ pre_sim,
             const float* __restrict__ x0T,
             const float* __restrict__ wT,
             const float* __restrict__ bias,
             float* __restrict__ out) {
    __shared__ __align__(16) u16 smem[2][2 * STEP_E];   // 114,688 B (K-loop dbuf / om)
    __shared__ __align__(16) float red2[2 * 8 * 64 * 9]; // 36,864 B (handoff / oc-red)

    int bid  = blockIdx.x;                        // 256 blocks
    int work = ((bid & 7) << 5) + (bid >> 3);     // XCD-chunked
    int b    = work >> 7;
    int px0  = (work & 127) << 7;                 // one image row (128 px)

    int tid  = threadIdx.x;
    int lane = tid & 63;
    int wid  = tid >> 6;             // 0..15
    int kidc = wid & 1;              // ic-chunk
    int wcol = (wid >> 1) & 1;
    int wrow = wid >> 2;             // 0..3

    fx4 acc[2][7];
#pragma unroll
    for (int mf = 0; mf < 2; ++mf)
#pragma unroll
        for (int nf = 0; nf < 7; ++nf) acc[mf][nf] = fx4{0.f, 0.f, 0.f, 0.f};

    // A base addresses (padded layout)
    int pA    = px0 + wrow * 32 + (lane & 15);
    int klane = (lane >> 4) << 3;
    int base0 = (((pA >> 7) + 1) * PW + (pA & (W - 1)) + 1) * C + kidc * 32 + klane;
    int base1 = base0 + 16 * C;      // mf=1 (+16 px, same row)

    const u16* xh_b = x1p_hi + (size_t)b * PADP * C;
    const u16* xl_b = x1p_lo + (size_t)b * PADP * C;

    // staging role: 14 waves x 4 insts cover 56 x 1KB slots (both chunks)
    bool stager = (wid < 14);
    int  soff[4];
#pragma unroll
    for (int k = 0; k < 4; ++k) {
        int s  = wid * 4 + k;        // 0..55
        int cs = s / 28;             // chunk
        int wi = s - cs * 28;
        soff[k] = cs * STEP_E + wi * 512 + lane * 8;
    }

    // prologue: stage tap 0 (both chunks), load A(tap 0)
    if (stager) {
#pragma unroll
        for (int k = 0; k < 4; ++k) {
            __builtin_amdgcn_global_load_lds(
                (const __attribute__((address_space(1))) u16*)(wB + soff[k]),
                (__attribute__((address_space(3))) u16*)(&smem[0][0] + soff[k]),
                16, 0, 0);
        }
    }
    bfx8 ahc0 = *(const bfx8*)(xh_b + base0 + TAPD[0]);
    bfx8 ahc1 = *(const bfx8*)(xh_b + base1 + TAPD[0]);
    bfx8 alc0 = *(const bfx8*)(xl_b + base0 + TAPD[0]);
    bfx8 alc1 = *(const bfx8*)(xl_b + base1 + TAPD[0]);
    __syncthreads();

#pragma unroll
    for (int t = 0; t < 9; ++t) {
        bfx8 ahn0, ahn1, aln0, aln1;
        if (t < 8) {
            if (stager) {
                const u16* src = wB + (size_t)(t + 1) * 2 * STEP_E;
                u16* dst = &smem[(t + 1) & 1][0];
#pragma unroll
                for (int k = 0; k < 4; ++k) {
                    __builtin_amdgcn_global_load_lds(
                        (const __attribute__((address_space(1))) u16*)(src + soff[k]),
                        (__attribute__((address_space(3))) u16*)(dst + soff[k]),
                        16, 0, 0);
                }
            }
            int d = TAPD[t + 1];
            ahn0 = *(const bfx8*)(xh_b + base0 + d);
            ahn1 = *(const bfx8*)(xh_b + base1 + d);
            aln0 = *(const bfx8*)(xl_b + base0 + d);
            aln1 = *(const bfx8*)(xl_b + base1 + d);
        }
        const u16* slab = &smem[t & 1][kidc * STEP_E];
#pragma unroll
        for (int nf = 0; nf < 7; ++nf) {
            const u16* bp = slab + (((wcol * 7 + nf) << 10) + (lane << 3));
            bfx8 bh = *(const bfx8*)bp;
            bfx8 bl = *(const bfx8*)(bp + 512);
            acc[0][nf] = __builtin_amdgcn_mfma_f32_16x16x32_bf16(ahc0, bh, acc[0][nf], 0, 0, 0);
            acc[0][nf] = __builtin_amdgcn_mfma_f32_16x16x32_bf16(alc0, bh, acc[0][nf], 0, 0, 0);
            acc[0][nf] = __builtin_amdgcn_mfma_f32_16x16x32_bf16(ahc0, bl, acc[0][nf], 0, 0, 0);
            acc[1][nf] = __builtin_amdgcn_mfma_f32_16x16x32_bf16(ahc1, bh, acc[1][nf], 0, 0, 0);
            acc[1][nf] = __builtin_amdgcn_mfma_f32_16x16x32_bf16(alc1, bh, acc[1][nf], 0, 0, 0);
            acc[1][nf] = __builtin_amdgcn_mfma_f32_16x16x32_bf16(ahc1, bl, acc[1][nf], 0, 0, 0);
        }
        __syncthreads();
        if (t < 8) {
            ahc0 = ahn0; ahc1 = ahn1; alc0 = aln0; alc1 = aln1;
        }
    }

    // ---- Phase 2: kid handoff (4 rounds via red2) + transform into om LDS --
    float* om = (float*)&smem[0][0];   // [px 128][OMS=217] floats
    int slot = wrow * 2 + wcol;        // 0..7
#pragma unroll
    for (int rnd = 0; rnd < 4; ++rnd) {
        int f0 = rnd * 4;
        int f1 = (f0 + 4 < 14) ? f0 + 4 : 14;
        if (kidc) {
#pragma unroll
            for (int f = 0; f < 4; ++f) {
                if (f0 + f < 14) {
                    int mf = (f0 + f) / 7, nf = (f0 + f) % 7;
                    *(fx4*)&red2[((slot * 4 + f) * 64 + lane) * 4] = acc[mf][nf];
                }
            }
        }
        __syncthreads();
        if (!kidc) {
#pragma unroll
            for (int f = 0; f < 4; ++f) {
                if (f0 + f < 14) {
                    int mf = (f0 + f) / 7, nf = (f0 + f) % 7;
                    fx4 v = acc[mf][nf] + *(fx4*)&red2[((slot * 4 + f) * 64 + lane) * 4];
                    int oc   = wcol * 112 + nf * 16 + (lane & 15);
                    int pixL = wrow * 32 + mf * 16 + ((lane >> 4) << 2);
                    if (oc < OM_C) {
                        float bb = b_om[oc];
                        int gp = px0 + pixL;
                        if (oc < OFF_C) {
                            size_t oi = (size_t)(b * OFF_C + oc) * HW + gp;
                            float4 po = *(const float4*)&pre_offset[oi];
                            om[(pixL + 0) * OMS + oc] = MRM * tanhf(v[0] + bb) + po.x;
                            om[(pixL + 1) * OMS + oc] = MRM * tanhf(v[1] + bb) + po.y;
                            om[(pixL + 2) * OMS + oc] = MRM * tanhf(v[2] + bb) + po.z;
                            om[(pixL + 3) * OMS + oc] = MRM * tanhf(v[3] + bb) + po.w;
                        } else {
                            size_t mi = (size_t)(b * MSK_C + oc - OFF_C) * HW + gp;
                            float4 ps = *(const float4*)&pre_sim[mi];
                            om[(pixL + 0) * OMS + oc] = 1.0f / (1.0f + expf(-(v[0] + bb) * ps.x));
                            om[(pixL + 1) * OMS + oc] = 1.0f / (1.0f + expf(-(v[1] + bb) * ps.y));
                            om[(pixL + 2) * OMS + oc] = 1.0f / (1.0f + expf(-(v[2] + bb) * ps.z));
                            om[(pixL + 3) * OMS + oc] = 1.0f / (1.0f + expf(-(v[3] + bb) * ps.w));
                        }
                    }
                }
            }
        }
        __syncthreads();
    }

    // ---- Phase 3: deform conv. wave = (pxhalf, group g). ----
    int pxhalf = __builtin_amdgcn_readfirstlane(wid >> 3);
    int g      = __builtin_amdgcn_readfirstlane(wid & 7);
    int pxL = (pxhalf << 6) + lane;
    int p   = px0 + pxL;
    int h = p >> 7;
    int w = p & (W - 1);

    float acc2[O];
#pragma unroll
    for (int o = 0; o < O; ++o) acc2[o] = 0.0f;

    const float* xg = x0T + ((size_t)(b * DG + g) * HW) * CG;
    const float* omp = om + (size_t)pxL * OMS;

#pragma unroll
    for (int i = 0; i < KK; ++i) {
        int gi = g * KK + i;
        float offy = omp[2 * gi];
        float offx = omp[2 * gi + 1];
        float m    = omp[OFF_C + gi];

        float py = offy + (float)(h - 1 + i / 3);
        float px = offx + (float)(w - 1 + i % 3);
        float fy = floorf(py), fx = floorf(px);
        float ly = py - fy, lx = px - fx;
        float hy = 1.0f - ly, hx = 1.0f - lx;
        int y0 = (int)fy, x0i = (int)fx;
        int y1 = y0 + 1, x1i = x0i + 1;
        bool vy0 = (y0 >= 0) && (y0 < H);
        bool vy1 = (y1 >= 0) && (y1 < H);
        bool vx0 = (x0i >= 0) && (x0i < W);
        bool vx1 = (x1i >= 0) && (x1i < W);
        int cy0 = min(max(y0, 0), H - 1), cy1 = min(max(y1, 0), H - 1);
        int cx0 = min(max(x0i, 0), W - 1), cx1 = min(max(x1i, 0), W - 1);
        float w00 = hy * hx * ((vy0 && vx0) ? 1.0f : 0.0f) * m;
        float w01 = hy * lx * ((vy0 && vx1) ? 1.0f : 0.0f) * m;
        float w10 = ly * hx * ((vy1 && vx0) ? 1.0f : 0.0f) * m;
        float w11 = ly * lx * ((vy1 && vx1) ? 1.0f : 0.0f) * m;
        int i00 = cy0 * W + cx0, i01 = cy0 * W + cx1;
        int i10 = cy1 * W + cx0, i11 = cy1 * W + cx1;

        const float4* A  = (const float4*)(xg + (size_t)i00 * CG);
        const float4* Bc = (const float4*)(xg + (size_t)i01 * CG);
        const float4* Cc = (const float4*)(xg + (size_t)i10 * CG);
        const float4* Dc = (const float4*)(xg + (size_t)i11 * CG);
        float4 a0 = A[0],  a1 = A[1];
        float4 b0 = Bc[0], b1 = Bc[1];
        float4 c0 = Cc[0], c1 = Cc[1];
        float4 d0 = Dc[0], d1 = Dc[1];

        float v[CG];
        v[0] = w00 * a0.x + w01 * b0.x + w10 * c0.x + w11 * d0.x;
        v[1] = w00 * a0.y + w01 * b0.y + w10 * c0.y + w11 * d0.y;
        v[2] = w00 * a0.z + w01 * b0.z + w10 * c0.z + w11 * d0.z;
        v[3] = w00 * a0.w + w01 * b0.w + w10 * c0.w + w11 * d0.w;
        v[4] = w00 * a1.x + w01 * b1.x + w10 * c1.x + w11 * d1.x;
        v[5] = w00 * a1.y + w01 * b1.y + w10 * c1.y + w11 * d1.y;
        v[6] = w00 * a1.z + w01 * b1.z + w10 * c1.z + w11 * d1.z;
        v[7] = w00 * a1.w + w01 * b1.w + w10 * c1.w + w11 * d1.w;

        const float* wrow_ = wT + (size_t)(gi * CG) * O;   // wave-uniform
#pragma unroll
        for (int c = 0; c < CG; ++c) {
#pragma unroll
            for (int o = 0; o < O; ++o)
                acc2[o] = fmaf(v[c], wrow_[c * O + o], acc2[o]);
        }
    }

    // oc reduction per pxhalf group via red2 (pad-9, conflict-free).
#pragma unroll
    for (int chunk = 0; chunk < 8; ++chunk) {
        float* sl = &red2[((pxhalf * 8 + g) * 64 + lane) * 9];
#pragma unroll
        for (int j = 0; j < 8; ++j) sl[j] = acc2[chunk * 8 + j];
        __syncthreads();
        float s = 0.0f;
#pragma unroll
        for (int wv = 0; wv < 8; ++wv)
            s += red2[((pxhalf * 8 + wv) * 64 + lane) * 9 + g];
        int oc = chunk * 8 + g;
        out[((size_t)b * O + oc) * HW + p] = s + bias[oc];
        __syncthreads();
    }
}

// ---------------- Launch ----------------
extern "C" void kernel_launch(void* const* d_in, const int* in_sizes, int n_in,
                              void* d_out, int out_size, void* d_ws, size_t ws_size,
                              hipStream_t stream) {
    (void)in_sizes; (void)n_in; (void)out_size; (void)ws_size;
    const float* x0         = (const float*)d_in[0];
    const float* x1         = (const float*)d_in[1];
    const float* pre_offset = (const float*)d_in[2];
    const float* pre_sim    = (const float*)d_in[3];
    const float* weight     = (const float*)d_in[4];
    const float* bias       = (const float*)d_in[5];
    const float* w_om       = (const float*)d_in[6];
    const float* b_om       = (const float*)d_in[7];
    float* out = (float*)d_out;

    // ws layout: wT | x1p_hi | x1p_lo | wB | x0T  (~17.7 MB, no aliasing)
    float* wT     = (float*)d_ws;                       // 36864 floats
    u16*   x1p_hi = (u16*)(wT + WT_N);                  // X1P_N u16
    u16*   x1p_lo = x1p_hi + (size_t)X1P_N;             // X1P_N u16
    u16*   wB     = x1p_lo + (size_t)X1P_N;             // WB_N u16
    float* x0T    = (float*)(wB + (size_t)WB_N);        // X0T_N floats

    {
        int total = WT_N + B * HW + B * PADP + WB_N;   // 361480
        prep1_kernel<<<(total + 255) / 256, 256, 0, stream>>>(
            weight, w_om, x1, wT, x1p_hi, x1p_lo, wB);
    }
    {
        prep2_kernel<<<X0T_N / 256, 256, 0, stream>>>(x0, x0T);
    }
    {
        fused_kernel<<<256, 1024, 0, stream>>>(
            x1p_hi, x1p_lo, wB, b_om, pre_offset, pre_sim,
            x0T, wT, bias, out);
    }
}